// Round 1
// baseline (116.009 us; speedup 1.0000x reference)
//
#include <hip/hip_runtime.h>
#include <hip/hip_bf16.h>

// CovPooling: B=4096 graphs, n=512 nodes/graph, D=64 features.
// cov = X^T X / n - mu mu^T, upper triangle packed (2080 per graph).

#define DD      64
#define NPG     512
#define CHUNK   256
#define XSTRIDE 264   // ushorts per Xt row: 256 nodes + 8 pad = 528 B (== 16 mod 128)

typedef __bf16 bf16x8 __attribute__((ext_vector_type(8)));
typedef float  f32x4  __attribute__((ext_vector_type(4)));

__device__ __forceinline__ unsigned int f2bf_pack(float a, float b) {
  // RNE f32->bf16, pack a into low 16, b into high 16
  unsigned int ua = __builtin_bit_cast(unsigned int, a);
  unsigned int ub = __builtin_bit_cast(unsigned int, b);
  ua = ua + 0x7fffu + ((ua >> 16) & 1u);
  ub = ub + 0x7fffu + ((ub >> 16) & 1u);
  return (ua >> 16) | (ub & 0xffff0000u);
}

__global__ __launch_bounds__(256, 4)
void cov_pool_kernel(const float* __restrict__ X, float* __restrict__ out) {
  // Transposed bf16 tile: Xt[dim][node_in_chunk], row stride 264 ushorts (528 B).
  __shared__ __align__(16) unsigned short Xt[DD * XSTRIDE];
  __shared__ float sumbuf[4][DD];
  __shared__ float mu[DD];

  const int t    = threadIdx.x;
  const int lane = t & 63;
  const int w    = t >> 6;            // wave id 0..3
  const long g   = blockIdx.x;
  const float* Xg = X + g * (long)(NPG * DD);

  const int dimq = lane & 15;         // fragment row/col within 16-tile
  const int kgrp = (lane >> 4) * 8;   // fragment k-group base

  float csum = 0.f;                   // fp32 column sum for dim `lane`
  f32x4 acc[4];
  f32x4 zero = {0.f, 0.f, 0.f, 0.f};
  acc[0] = zero; acc[1] = zero; acc[2] = zero; acc[3] = zero;

  for (int half = 0; half < 2; ++half) {
    // ---- stage CHUNK nodes: coalesced dword column loads -> bf16 transposed LDS ----
    #pragma unroll 4
    for (int it = 0; it < CHUNK / 16; ++it) {
      const int nc = it * 16 + w * 4;            // in-chunk node base (4 nodes)
      const int n  = half * CHUNK + nc;          // absolute node
      const float* p = Xg + (long)n * DD + lane; // wave reads one 256B node row per load
      float f0 = p[0];
      float f1 = p[DD];
      float f2 = p[2 * DD];
      float f3 = p[3 * DD];
      csum += (f0 + f1) + (f2 + f3);
      uint2 v;
      v.x = f2bf_pack(f0, f1);
      v.y = f2bf_pack(f2, f3);
      *(uint2*)&Xt[lane * XSTRIDE + nc] = v;     // 8B write along node dim
    }
    __syncthreads();

    // ---- MFMA accumulate over this chunk (K = 256, steps of 32) ----
    #pragma unroll 2
    for (int kk = 0; kk < CHUNK / 32; ++kk) {
      const int kb = kk * 32 + kgrp;
      const bf16x8 A   = *(const bf16x8*)&Xt[(w * 16 + dimq) * XSTRIDE + kb];
      const bf16x8 fb0 = *(const bf16x8*)&Xt[( 0 + dimq) * XSTRIDE + kb];
      const bf16x8 fb1 = *(const bf16x8*)&Xt[(16 + dimq) * XSTRIDE + kb];
      const bf16x8 fb2 = *(const bf16x8*)&Xt[(32 + dimq) * XSTRIDE + kb];
      const bf16x8 fb3 = *(const bf16x8*)&Xt[(48 + dimq) * XSTRIDE + kb];
      if (w <= 0) acc[0] = __builtin_amdgcn_mfma_f32_16x16x32_bf16(A, fb0, acc[0], 0, 0, 0);
      if (w <= 1) acc[1] = __builtin_amdgcn_mfma_f32_16x16x32_bf16(A, fb1, acc[1], 0, 0, 0);
      if (w <= 2) acc[2] = __builtin_amdgcn_mfma_f32_16x16x32_bf16(A, fb2, acc[2], 0, 0, 0);
      acc[3] = __builtin_amdgcn_mfma_f32_16x16x32_bf16(A, fb3, acc[3], 0, 0, 0);
    }
    __syncthreads();   // protect Xt before next half's staging
  }

  // ---- column sums -> mean ----
  sumbuf[w][lane] = csum;
  __syncthreads();
  if (t < DD) {
    mu[t] = (sumbuf[0][t] + sumbuf[1][t] + sumbuf[2][t] + sumbuf[3][t]) * (1.f / NPG);
  }
  __syncthreads();

  // ---- epilogue: cov = acc/n - mu_i mu_j, write packed upper triangle ----
  const float inv_n = 1.f / NPG;
  float* og = out + g * 2080L;
  const int rbase = w * 16 + (lane >> 4) * 4;   // C row = (lane>>4)*4 + reg
  #pragma unroll
  for (int tn = 0; tn < 4; ++tn) {
    if (tn < w) continue;                       // only upper-triangle tiles
    const int j = tn * 16 + dimq;               // C col = lane & 15
    const float muj = mu[j];
    #pragma unroll
    for (int r = 0; r < 4; ++r) {
      const int i = rbase + r;
      if (j >= i) {
        const float v = acc[tn][r] * inv_n - mu[i] * muj;
        og[i * DD - (i * (i - 1)) / 2 + (j - i)] = v;
      }
    }
  }
}

extern "C" void kernel_launch(void* const* d_in, const int* in_sizes, int n_in,
                              void* d_out, int out_size, void* d_ws, size_t ws_size,
                              hipStream_t stream) {
  const float* X = (const float*)d_in[0];
  float* out = (float*)d_out;
  const int N = in_sizes[0] / DD;     // total nodes
  const int B = N / NPG;              // graphs
  cov_pool_kernel<<<dim3(B), dim3(256), 0, stream>>>(X, out);
}